// Round 1
// 200.807 us; speedup vs baseline: 1.0047x; 1.0047x over previous
//
#include <hip/hip_runtime.h>
#include <hip/hip_bf16.h>
#include <math.h>

typedef __attribute__((ext_vector_type(8))) short bf16x8;
typedef __attribute__((ext_vector_type(4))) short bf16x4;
typedef __attribute__((ext_vector_type(4))) float floatx4;

constexpr int kN  = 4096;
constexpr int kD  = 768;
constexpr int kH  = 12;
constexpr int kHD = 64;
constexpr int k3D = 2304;
// Q pre-scale: (1/sqrt(64)) * log2(e) so softmax runs in exp2 domain with no muls
constexpr float kQScale = 0.18033688011112042f;

static __device__ __forceinline__ short f2b(float f) {
    __hip_bfloat16 h = __float2bfloat16(f);
    return *reinterpret_cast<short*>(&h);
}

static __device__ __forceinline__ float fast_exp2(float x) {
#if __has_builtin(__builtin_amdgcn_exp2f)
    return __builtin_amdgcn_exp2f(x);
#else
    return exp2f(x);
#endif
}

// Async global->LDS DMA, 16B per lane. LDS dst is wave-uniform base + lane*16.
static __device__ __forceinline__ void async_copy16(const void* g, void* l) {
    __builtin_amdgcn_global_load_lds(
        (const __attribute__((address_space(1))) void*)g,
        (__attribute__((address_space(3))) void*)l, 16, 0, 0);
}

// Fused prep: section 0 = x fp32->bf16; section 1 = W_qkv transpose->bf16;
// section 2 = W_out transpose->bf16. One launch instead of three.
constexpr int kBlkX  = 1536;            // (4096*768/8)/256
constexpr int kBlkWq = 72 * 24;         // (2304/32) x (768/32)
constexpr int kBlkWo = 24 * 24;         // (768/32) x (768/32)

__global__ __launch_bounds__(256)
void prep(const float* __restrict__ x, const float* __restrict__ Wq,
          const float* __restrict__ Wo, short* __restrict__ Xb,
          short* __restrict__ WqT, short* __restrict__ WoT)
{
    const int bid = blockIdx.x;
    const int tid = threadIdx.x;
    if (bid < kBlkX) {
        const int i = bid * 256 + tid;
        const float4* s = reinterpret_cast<const float4*>(x + (size_t)i * 8);
        float4 a = s[0], b = s[1];
        bf16x8 v;
        v[0] = f2b(a.x); v[1] = f2b(a.y); v[2] = f2b(a.z); v[3] = f2b(a.w);
        v[4] = f2b(b.x); v[5] = f2b(b.y); v[6] = f2b(b.z); v[7] = f2b(b.w);
        *reinterpret_cast<bf16x8*>(Xb + (size_t)i * 8) = v;
        return;
    }
    // transpose sections: src[R][C] -> dst[C][R]
    const float* src; short* dst; int R, C, bx, by;
    if (bid < kBlkX + kBlkWq) {
        const int local = bid - kBlkX;
        src = Wq; dst = WqT; R = kD; C = k3D; bx = local % 72; by = local / 72;
    } else {
        const int local = bid - kBlkX - kBlkWq;
        src = Wo; dst = WoT; R = kD; C = kD; bx = local % 24; by = local / 24;
    }
    __shared__ float t[32][33];
    const int c0 = bx * 32, r0 = by * 32;
    const int tx = tid & 31, ty = tid >> 5;
    #pragma unroll
    for (int i = ty; i < 32; i += 8)
        t[i][tx] = src[(size_t)(r0 + i) * C + c0 + tx];
    __syncthreads();
    #pragma unroll
    for (int i = ty; i < 32; i += 8)
        dst[(size_t)(c0 + i) * R + r0 + tx] = f2b(t[tx][i]);
}

// C[M x N] = A[M x K] * BT[N x K]^T, bf16 in, fp32 acc. 128x128 tile, BK=32.
// m97 structure: async global->LDS staging (16B), unpadded tiles, XOR swizzle.
// MODE 0: Cout fp32 = C + bias;  MODE 1: scatter bf16 Qh(*kQScale), Kh, Vt[h][d][n]
template<int MODE>
__device__ __forceinline__
void gemm_core(const short* __restrict__ A, const short* __restrict__ BT,
               const float* __restrict__ bias, float* __restrict__ Cout,
               short* __restrict__ Qh, short* __restrict__ Kh, short* __restrict__ Vt,
               int N, int K)
{
    const int bm   = blockIdx.x * 128;
    const int bn   = blockIdx.y * 128;
    const int tid  = threadIdx.x;
    const int wave = tid >> 6;
    const int lane = tid & 63;
    const int l15  = lane & 15;
    const int quad = lane >> 4;
    const int l3   = l15 & 3;

    __shared__ alignas(16) short As[128 * 32];
    __shared__ alignas(16) short Bs[128 * 32];

    floatx4 acc[4][4] = {};
    const int wm = (wave >> 1) * 64;
    const int wn = (wave & 1) * 64;

    // staging: 16 rows per issue (4 lanes/row), 2 issues/wave per buffer
    const int srl = lane >> 2;               // row within issue group (0..15)
    const int scc = (lane & 3) ^ (srl & 3);  // swizzled source chunk

    for (int k0 = 0; k0 < K; k0 += 32) {
        __syncthreads();
        #pragma unroll
        for (int j = 0; j < 2; ++j) {
            const int rs = 32 * wave + 16 * j;     // wave-uniform row start
            async_copy16(&A [(size_t)(bm + rs + srl) * K + k0 + 8 * scc], &As[rs * 32]);
            async_copy16(&BT[(size_t)(bn + rs + srl) * K + k0 + 8 * scc], &Bs[rs * 32]);
        }
        __syncthreads();

        bf16x8 af[4], bfr[4];
        #pragma unroll
        for (int mt = 0; mt < 4; ++mt)
            af[mt] = *reinterpret_cast<const bf16x8*>(&As[(wm + 16 * mt + l15) * 32 + 8 * (quad ^ l3)]);
        #pragma unroll
        for (int nt = 0; nt < 4; ++nt)
            bfr[nt] = *reinterpret_cast<const bf16x8*>(&Bs[(wn + 16 * nt + l15) * 32 + 8 * (quad ^ l3)]);
        #pragma unroll
        for (int mt = 0; mt < 4; ++mt)
            #pragma unroll
            for (int nt = 0; nt < 4; ++nt)
                acc[mt][nt] = __builtin_amdgcn_mfma_f32_16x16x32_bf16(af[mt], bfr[nt], acc[mt][nt], 0, 0, 0);
    }

    #pragma unroll
    for (int mt = 0; mt < 4; ++mt) {
        #pragma unroll
        for (int nt = 0; nt < 4; ++nt) {
            #pragma unroll
            for (int r = 0; r < 4; ++r) {
                const int row = bm + wm + mt * 16 + 4 * quad + r;
                const int col = bn + wn + nt * 16 + l15;
                float v = acc[mt][nt][r];
                if (MODE == 0) {
                    Cout[(size_t)row * N + col] = v + bias[col];
                } else {
                    const int proj   = col / kD;       // blocks never span projections
                    const int within = col - proj * kD;
                    const int h = within >> 6;
                    const int d = within & 63;
                    if (proj == 0)      Qh[((size_t)h * kN + row) * kHD + d] = f2b(v * kQScale);
                    else if (proj == 1) Kh[((size_t)h * kN + row) * kHD + d] = f2b(v);
                    else                Vt[((size_t)h * kHD + d) * kN + row] = f2b(v);
                }
            }
        }
    }
}

__global__ __launch_bounds__(256)
void gemm_qkv(const short* __restrict__ A, const short* __restrict__ BT,
              short* __restrict__ Qh, short* __restrict__ Kh, short* __restrict__ Vt)
{
    gemm_core<1>(A, BT, nullptr, nullptr, Qh, Kh, Vt, k3D, kD);
}

__global__ __launch_bounds__(256)
void gemm_out(const short* __restrict__ A, const short* __restrict__ BT,
              const float* __restrict__ bias, float* __restrict__ Cout)
{
    gemm_core<0>(A, BT, bias, Cout, nullptr, nullptr, nullptr, kD, kD);
}

// Flash attention, no-max softmax, S^T formulation.
// v2: 2-deep double-buffered K/V pipeline with ONE barrier per 64-wide KV tile
//     (stage t+1 right after the barrier, compute tile t underneath the DMA;
//     the barrier's vmcnt drain only waits on loads issued a full phase ago),
//     softmax denominator accumulated on the MFMA pipe via an all-ones B
//     fragment (C-layout lands denom[4*quad+r] in exactly the lane that
//     divides by it -> no shuffles, no per-tile psum VALU adds),
//     s_setprio(1) around MFMA clusters.
// LDS = Ks 2x8K + Vs 2x8K + Pm 8K = 40KB -> exactly 4 blocks/CU (16 waves).
// Grid (N/64, H), 4 waves x 16 Q rows, BN=64 KV tile.
__global__ __launch_bounds__(256)
void attn(const short* __restrict__ Qh, const short* __restrict__ Kh,
          const short* __restrict__ Vt, short* __restrict__ AO)
{
    const int h    = blockIdx.y;
    const int q0   = blockIdx.x * 64;
    const int tid  = threadIdx.x;
    const int wave = tid >> 6;
    const int lane = tid & 63;
    const int l15  = lane & 15;
    const int quad = lane >> 4;
    const int lx   = l15 & 7;

    __shared__ alignas(16) short Ks[2][64 * 64];  // K tile [kv][d], swizzled
    __shared__ alignas(16) short Vs[2][64 * 64];  // V^T tile [d][kv], swizzled
    __shared__ alignas(16) short Pm[4][16 * 64];  // per-wave P [m=l15][kv], swizzled

    // Q fragments (pre-scaled by kQScale), held for the whole sweep.
    // Used as the B-operand of QK^T (B-frag lane map == A-frag lane map).
    const int qrow = q0 + 16 * wave + l15;
    const size_t qbase = ((size_t)h * kN + qrow) * kHD;
    bf16x8 qf[2];
    qf[0] = *reinterpret_cast<const bf16x8*>(&Qh[qbase + quad * 8]);
    qf[1] = *reinterpret_cast<const bf16x8*>(&Qh[qbase + 32 + quad * 8]);

    // all-ones B fragment: mfma(pa, ones) sums each P row -> softmax denom,
    // and its C-layout puts denom[row=4*quad+r] in reg r of every lane.
    bf16x8 onesf;
    #pragma unroll
    for (int i = 0; i < 8; ++i) onesf[i] = (short)0x3F80;

    floatx4 oacc[4] = {};
    floatx4 dacc = {};

    // staging lane constants: each issue covers 8 rows of 128B; physical
    // chunk (lane&7) holds logical chunk (lane&7)^(row&7)  (XOR swizzle)
    const int srl = lane >> 3;              // row within 8-row issue
    const int scc = (lane & 7) ^ srl;       // swizzled source chunk

    short* Pw = Pm[wave];                   // this wave's 16 x 64 P rows

    const size_t kbase = (size_t)h * kN * kHD;   // Kh [h][n][d]
    const size_t vbase = (size_t)h * kHD * kN;   // Vt [h][d][n]

    auto stage = [&](int b, int kv0) {
        #pragma unroll
        for (int j = 0; j < 2; ++j) {
            const int r0 = 16 * wave + 8 * j;       // 8 K rows (kv) / 8 V rows (d)
            async_copy16(&Kh[kbase + (size_t)(kv0 + r0 + srl) * kHD + 8 * scc],
                         &Ks[b][r0 * 64]);
            async_copy16(&Vt[vbase + (size_t)(r0 + srl) * kN + kv0 + 8 * scc],
                         &Vs[b][r0 * 64]);
        }
    };

    constexpr int kNT = kN / 64;
    int cur = 0;
    stage(0, 0);

    for (int t = 0; t < kNT; ++t) {
        // drains this wave's vmcnt (loads issued at t-1, already covered by
        // compute) and makes buf[cur] visible to all waves; also guarantees
        // everyone is done reading buf[cur^1] before we overwrite it.
        __syncthreads();
        if (t + 1 < kNT) stage(cur ^ 1, (t + 1) * 64);

        const short* Kc = Ks[cur];
        const short* Vc = Vs[cur];

        // S^T = K Q^T (64 kv x 16 m per wave): swap operands, same fragments
        floatx4 sacc[4] = {};
        __builtin_amdgcn_s_setprio(1);
        #pragma unroll
        for (int nt = 0; nt < 4; ++nt) {
            #pragma unroll
            for (int s = 0; s < 2; ++s) {
                bf16x8 kf = *reinterpret_cast<const bf16x8*>(
                    &Kc[(16 * nt + l15) * 64 + 8 * ((4 * s + quad) ^ lx)]);
                sacc[nt] = __builtin_amdgcn_mfma_f32_16x16x32_bf16(kf, qf[s], sacc[nt], 0, 0, 0);
            }
        }
        __builtin_amdgcn_s_setprio(0);

        // p = exp2(s^T); lane holds row m=l15, kv = 16nt+4quad+r -> pack 4 r's
        // into one b64 write at chunk c=2nt+(quad>>1), swizzled c^lx.
        #pragma unroll
        for (int nt = 0; nt < 4; ++nt) {
            const float p0 = fast_exp2(sacc[nt][0]);
            const float p1 = fast_exp2(sacc[nt][1]);
            const float p2 = fast_exp2(sacc[nt][2]);
            const float p3 = fast_exp2(sacc[nt][3]);
            bf16x4 pk;
            pk[0] = f2b(p0); pk[1] = f2b(p1); pk[2] = f2b(p2); pk[3] = f2b(p3);
            const int c = 2 * nt + (quad >> 1);
            *reinterpret_cast<bf16x4*>(
                &Pw[l15 * 64 + 8 * (c ^ lx) + 4 * (quad & 1)]) = pk;
        }
        // no barrier: Pw is wave-private; per-wave DS ops complete in order

        // PV: P as A-frag (one b128 per s), V^T rows as B-frag; denom via ones
        __builtin_amdgcn_s_setprio(1);
        #pragma unroll
        for (int s = 0; s < 2; ++s) {
            bf16x8 pa = *reinterpret_cast<const bf16x8*>(
                &Pw[l15 * 64 + 8 * ((4 * s + quad) ^ lx)]);
            dacc = __builtin_amdgcn_mfma_f32_16x16x32_bf16(pa, onesf, dacc, 0, 0, 0);
            #pragma unroll
            for (int dt = 0; dt < 4; ++dt) {
                bf16x8 vv = *reinterpret_cast<const bf16x8*>(
                    &Vc[(16 * dt + l15) * 64 + 8 * ((4 * s + quad) ^ lx)]);
                oacc[dt] = __builtin_amdgcn_mfma_f32_16x16x32_bf16(pa, vv, oacc[dt], 0, 0, 0);
            }
        }
        __builtin_amdgcn_s_setprio(0);

        cur ^= 1;
    }

    // dacc[r] = denom for Q-row 4*quad+r (identical across l15) -> no shuffles
    float inv[4];
    #pragma unroll
    for (int r = 0; r < 4; ++r) inv[r] = 1.0f / dacc[r];

    #pragma unroll
    for (int dt = 0; dt < 4; ++dt) {
        #pragma unroll
        for (int r = 0; r < 4; ++r) {
            const int row = q0 + 16 * wave + 4 * quad + r;
            const int col = h * kHD + 16 * dt + l15;
            AO[(size_t)row * kD + col] = f2b(oacc[dt][r] * inv[r]);
        }
    }
}

extern "C" void kernel_launch(void* const* d_in, const int* in_sizes, int n_in,
                              void* d_out, int out_size, void* d_ws, size_t ws_size,
                              hipStream_t stream)
{
    const float* x     = (const float*)d_in[0];  // (4096, 768) fp32
    const float* W_qkv = (const float*)d_in[1];  // (768, 2304) fp32
    const float* W_out = (const float*)d_in[2];  // (768, 768)  fp32
    const float* b_out = (const float*)d_in[3];  // (768,)      fp32
    float* out = (float*)d_out;                  // (4096, 768) fp32

    const size_t HNHD = (size_t)kH * kN * kHD;   // 3,145,728 shorts per tensor
    short* Qh    = (short*)d_ws;                 // [H][N][64]
    short* Kh    = Qh + HNHD;
    short* Vt    = Kh + HNHD;                    // [H][64][N]
    short* Xb    = Vt + HNHD;                    // x bf16 [N][768]; reused as AO
    short* WqkvT = Xb + (size_t)kN * kD;         // [2304][768]
    short* WoutT = WqkvT + (size_t)k3D * kD;     // [768][768]
    short* AO    = Xb;                           // overlay: Xb dead after QKV gemm
    (void)in_sizes; (void)n_in; (void)out_size; (void)ws_size;

    // 0) fused conversions/transposes (one launch)
    prep<<<dim3(kBlkX + kBlkWq + kBlkWo), dim3(256), 0, stream>>>(
        x, W_qkv, W_out, Xb, WqkvT, WoutT);

    // 1) QKV projection + head scatter (Q pre-scaled, V transposed)
    gemm_qkv<<<dim3(kN / 128, k3D / 128), dim3(256), 0, stream>>>(
        Xb, WqkvT, Qh, Kh, Vt);
    // 2) flash attention
    attn<<<dim3(kN / 64, kH), dim3(256), 0, stream>>>(Qh, Kh, Vt, AO);
    // 3) output projection + bias -> fp32
    gemm_out<<<dim3(kN / 128, kD / 128), dim3(256), 0, stream>>>(
        AO, WoutT, b_out, out);
}